// Round 3
// baseline (421.007 us; speedup 1.0000x reference)
//
#include <hip/hip_runtime.h>
#include <stdint.h>
#include <stddef.h>

typedef _Float16 f16;
typedef _Float16 f16x8 __attribute__((ext_vector_type(8)));
typedef _Float16 f16x4 __attribute__((ext_vector_type(4)));
typedef float f32x4 __attribute__((ext_vector_type(4)));

__device__ __forceinline__ void gload16(const void* g, void* l) {
    auto gp = (const __attribute__((address_space(1))) uint32_t*)(uintptr_t)g;
    auto lp = (__attribute__((address_space(3))) uint32_t*)(uintptr_t)l;
    __builtin_amdgcn_global_load_lds(gp, lp, 16, 0, 0);
}

__device__ __forceinline__ f16x4 cvt4(f32x4 v) {
    return f16x4{ (f16)v[0], (f16)v[1], (f16)v[2], (f16)v[3] };
}

// ---------------- prep: f32 -> f16 conversions --------------------------------
__global__ __launch_bounds__(256) void prep_k(const float* __restrict__ x,
                                              const float* __restrict__ wqkv,
                                              const float* __restrict__ wout,
                                              f16* __restrict__ xb,
                                              f16* __restrict__ wqb,
                                              f16* __restrict__ wob) {
    int tid = blockIdx.x * blockDim.x + threadIdx.x;
    int stride = gridDim.x * blockDim.x;
    for (int i = tid; i < 4194304; i += stride) {
        float4 v = ((const float4*)x)[i];
        *(f16x4*)(xb + (size_t)i * 4) = f16x4{ (f16)v.x, (f16)v.y, (f16)v.z, (f16)v.w };
    }
    for (int i = tid; i < 196608; i += stride) {
        float4 v = ((const float4*)wqkv)[i];
        *(f16x4*)(wqb + (size_t)i * 4) = f16x4{ (f16)v.x, (f16)v.y, (f16)v.z, (f16)v.w };
    }
    for (int i = tid; i < 65536; i += stride) {
        float4 v = ((const float4*)wout)[i];
        *(f16x4*)(wob + (size_t)i * 4) = f16x4{ (f16)v.x, (f16)v.y, (f16)v.z, (f16)v.w };
    }
}

// ---------------- 256x256 tile, BK=64, 8-wave read-ahead pipelined GEMM -------
// C[m][n] = sum_k A[m][k]*B[n][k], K=512 (8 K-tiles of BK=64), row stride 512.
// Schedule per K-tile (1 barrier, 1 vmcnt only):
//   P0: issue bf1 reads; issue ALL 8 stage loads (tile t+1 -> other buf); MFMA(afA,bf0)
//   P1: issue afB reads;                                                  MFMA(afA,bf1)
//   P2:                                                                   MFMA(afB,bf1)
//   P3: vmcnt(0); barrier; issue afA reads (next buf); MFMA(afB,bf0); issue bf0 reads (next buf)
// Reads for phase p+1 drain in the LDS pipe underneath phase p's MFMA cluster.

#define MFMA_Q(MH, NH, AF, BF) do {                                             \
    __builtin_amdgcn_s_setprio(1);                                              \
    if (swp) {                                                                  \
        _Pragma("unroll") for (int kk = 0; kk < 2; ++kk)                        \
        _Pragma("unroll") for (int mi = 0; mi < 4; ++mi)                        \
        _Pragma("unroll") for (int ni = 0; ni < 2; ++ni)                        \
            acc[(MH)*4+mi][(NH)*2+ni] = __builtin_amdgcn_mfma_f32_16x16x32_f16( \
                BF[ni][kk], AF[mi][kk], acc[(MH)*4+mi][(NH)*2+ni], 0, 0, 0);    \
    } else {                                                                    \
        _Pragma("unroll") for (int kk = 0; kk < 2; ++kk)                        \
        _Pragma("unroll") for (int mi = 0; mi < 4; ++mi)                        \
        _Pragma("unroll") for (int ni = 0; ni < 2; ++ni)                        \
            acc[(MH)*4+mi][(NH)*2+ni] = __builtin_amdgcn_mfma_f32_16x16x32_f16( \
                AF[mi][kk], BF[ni][kk], acc[(MH)*4+mi][(NH)*2+ni], 0, 0, 0);    \
    }                                                                           \
    __builtin_amdgcn_s_setprio(0);                                              \
} while (0)

#define RD_AFA(LA) do { _Pragma("unroll") for (int mi = 0; mi < 4; ++mi)        \
    _Pragma("unroll") for (int kk = 0; kk < 2; ++kk)                            \
        afA[mi][kk] = *(const f16x8*)((LA) + aoff[mi * 2 + kk]); } while (0)
#define RD_AFB(LA) do { _Pragma("unroll") for (int mi = 0; mi < 4; ++mi)        \
    _Pragma("unroll") for (int kk = 0; kk < 2; ++kk)                            \
        afB[mi][kk] = *(const f16x8*)((LA) + aoff[8 + mi * 2 + kk]); } while (0)
#define RD_BF0(LB) do { _Pragma("unroll") for (int ni = 0; ni < 2; ++ni)        \
    _Pragma("unroll") for (int kk = 0; kk < 2; ++kk)                            \
        bf0[ni][kk] = *(const f16x8*)((LB) + boff[ni * 2 + kk]); } while (0)
#define RD_BF1(LB) do { _Pragma("unroll") for (int ni = 0; ni < 2; ++ni)        \
    _Pragma("unroll") for (int kk = 0; kk < 2; ++kk)                            \
        bf1[ni][kk] = *(const f16x8*)((LB) + boff[4 + ni * 2 + kk]); } while (0)

#define STAGE_A(h, li, NB) gload16(srcA[(h)*2+(li)], &lds[NB][0][((h)*128+(li)*64+wid*8)*64])
#define STAGE_B(h, li, NB) gload16(srcB[(h)*2+(li)], &lds[NB][1][((h)*128+(li)*64+wid*8)*64])
#define STAGE_ALL(NB) do {                                                      \
    STAGE_A(0,0,NB); STAGE_A(0,1,NB); STAGE_B(0,0,NB); STAGE_B(0,1,NB);         \
    STAGE_B(1,0,NB); STAGE_B(1,1,NB); STAGE_A(1,0,NB); STAGE_A(1,1,NB); } while (0)

#define TILE(CB, NB, STG, FINAL) do {                                           \
    RD_BF1(&lds[CB][1][0]);                                                     \
    if (STG) STAGE_ALL(NB);                                                     \
    MFMA_Q(0, 0, afA, bf0);                                                     \
    RD_AFB(&lds[CB][0][0]);                                                     \
    MFMA_Q(0, 1, afA, bf1);                                                     \
    MFMA_Q(1, 1, afB, bf1);                                                     \
    if (!FINAL) {                                                               \
        asm volatile("s_waitcnt vmcnt(0)" ::: "memory");                        \
        __builtin_amdgcn_s_barrier();                                           \
        RD_AFA(&lds[NB][0][0]);                                                 \
    }                                                                           \
    MFMA_Q(1, 0, afB, bf0);                                                     \
    if (!FINAL) {                                                               \
        RD_BF0(&lds[NB][1][0]);                                                 \
        _Pragma("unroll") for (int z = 0; z < 4; ++z) { srcA[z] += 64; srcB[z] += 64; } \
    }                                                                           \
} while (0)

template <int MODE>
__global__ __launch_bounds__(512, 2) void g8_k(const f16* __restrict__ A0,
                                               const f16* __restrict__ B0,
                                               void* __restrict__ C0,
                                               void* __restrict__ C1,
                                               void* __restrict__ C2,
                                               const float* __restrict__ bias) {
    __shared__ f16 lds[2][2][16384];   // [buf][A/B][256 rows x 64 k], 128 KiB

    const int tid = threadIdx.x;
    const int lane = tid & 63;
    const int wid = tid >> 6;
    const int wr = wid >> 2;   // 0..1
    const int wc = wid & 3;    // 0..3

    int tm, tn, bh = 0;
    bool qk = false, swp;
    const int bid = blockIdx.x;
    if constexpr (MODE == 0) {
        int swz = (bid & 7) * 96 + (bid >> 3);          // 768 blocks, bijective
        tm = (swz / 6) * 256; tn = (swz % 6) * 256;
        qk = tn < 1024; swp = !qk;
    } else if constexpr (MODE == 1 || MODE == 2) {
        int swz = (bid & 7) * 32 + (bid >> 3);          // 256 blocks
        bh = swz >> 2; tm = ((swz >> 1) & 1) * 256; tn = (swz & 1) * 256;
        swp = (MODE == 1);
    } else {
        int swz = (bid & 7) * 32 + (bid >> 3);          // 256 blocks
        tm = (swz >> 1) * 256; tn = (swz & 1) * 256;
        swp = true;
    }

    const size_t bhoff = (MODE == 1 || MODE == 2) ? (size_t)bh * 262144 : 0;
    const f16* At = A0 + bhoff + (size_t)tm * 512;
    const f16* Bt = B0 + bhoff + (size_t)tn * 512;

    // staging source, pre-swizzled: chunk c8 = (tid&7) ^ s(r), s(r)=(r&7)^((r>>3)&7)
    const f16* srcA[4];
    const f16* srcB[4];
#pragma unroll
    for (int h = 0; h < 2; ++h)
#pragma unroll
        for (int li = 0; li < 2; ++li) {
            int r = h * 128 + li * 64 + (tid >> 3);
            int c8 = (tid & 7) ^ ((r & 7) ^ ((r >> 3) & 7));
            srcA[h * 2 + li] = At + (size_t)r * 512 + c8 * 8;
            srcB[h * 2 + li] = Bt + (size_t)r * 512 + c8 * 8;
        }

    // fragment LDS offsets (f16 units), swizzled reads
    int aoff[16];  // [mh][mi][kk]
    int boff[8];   // [nh][ni][kk]
#pragma unroll
    for (int mh = 0; mh < 2; ++mh)
#pragma unroll
        for (int mi = 0; mi < 4; ++mi) {
            int r = qk ? (mh * 128 + (lane & 15) * 8 + wr * 4 + mi)
                       : (mh * 128 + wr * 64 + mi * 16 + (lane & 15));
#pragma unroll
            for (int kk = 0; kk < 2; ++kk) {
                int c8 = (lane >> 4) + kk * 4;
                aoff[mh * 8 + mi * 2 + kk] = r * 64 + (c8 ^ ((r & 7) ^ ((r >> 3) & 7))) * 8;
            }
        }
#pragma unroll
    for (int nh = 0; nh < 2; ++nh)
#pragma unroll
        for (int ni = 0; ni < 2; ++ni) {
            int r = nh * 128 + wc * 32 + ni * 16 + (lane & 15);
#pragma unroll
            for (int kk = 0; kk < 2; ++kk) {
                int c8 = (lane >> 4) + kk * 4;
                boff[nh * 4 + ni * 2 + kk] = r * 64 + (c8 ^ ((r & 7) ^ ((r >> 3) & 7))) * 8;
            }
        }

    f32x4 acc[8][4] = {};
    f16x8 afA[4][2], afB[4][2], bf0[2][2], bf1[2][2];

    // ---- prologue: stage tile 0, drain, certify, pre-issue afA/bf0 reads
    STAGE_ALL(0);
#pragma unroll
    for (int z = 0; z < 4; ++z) { srcA[z] += 64; srcB[z] += 64; }
    asm volatile("s_waitcnt vmcnt(0)" ::: "memory");
    __builtin_amdgcn_s_barrier();
    RD_AFA(&lds[0][0][0]);
    RD_BF0(&lds[0][1][0]);

    // ---- main: tiles 0..5 in even/odd pairs, then t6 (even), t7 (final odd)
#pragma unroll 1
    for (int i = 0; i < 3; ++i) {
        TILE(0, 1, true, false);
        TILE(1, 0, true, false);
    }
    TILE(0, 1, true, false);
    TILE(1, 0, false, true);

    // ---------------- epilogues ----------------
    if constexpr (MODE == 0) {
        const int b = tm >> 12;
        if (qk) {
            f16* dst = (f16*)(tn < 512 ? C0 : C1);
            const int lt = (tm & 4095) >> 3;
            const int cb = (tn & 511) + wc * 32;
#pragma unroll
            for (int mf = 0; mf < 8; ++mf) {
                int h = wr * 4 + (mf & 3);
                int lh0 = lt + (mf >> 2) * 16 + (lane >> 4) * 4;
#pragma unroll
                for (int nf = 0; nf < 4; ++nf) {
                    int c = cb + (nf >> 1) * 128 + (nf & 1) * 16 + (lane & 15);
                    *(f16x4*)(dst + ((size_t)((b * 8 + h) * 512 + c)) * 512 + lh0) =
                        cvt4(acc[mf][nf]);
                }
            }
        } else {
            f16* dst = (f16*)C2;
#pragma unroll
            for (int mf = 0; mf < 8; ++mf) {
                int m = (tm & 4095) + (mf >> 2) * 128 + wr * 64 + (mf & 3) * 16 + (lane & 15);
                int h = m & 7;
                int lh = m >> 3;
#pragma unroll
                for (int nf = 0; nf < 4; ++nf) {
                    int d0 = (tn - 1024) + (nf >> 1) * 128 + wc * 32 + (nf & 1) * 16 + (lane >> 4) * 4;
                    *(f16x4*)(dst + ((size_t)((b * 8 + h) * 512 + lh)) * 512 + d0) =
                        cvt4(acc[mf][nf]);
                }
            }
        }
    } else if constexpr (MODE == 1) {
        f16* S = (f16*)C0 + (size_t)bh * 262144;
#pragma unroll
        for (int mf = 0; mf < 8; ++mf) {
            int cm = tm + (mf >> 2) * 128 + wr * 64 + (mf & 3) * 16 + (lane & 15);
#pragma unroll
            for (int nf = 0; nf < 4; ++nf) {
                int d0 = tn + (nf >> 1) * 128 + wc * 32 + (nf & 1) * 16 + (lane >> 4) * 4;
                *(f16x4*)(S + (size_t)cm * 512 + d0) = cvt4(acc[mf][nf] * 0.125f);
            }
        }
    } else if constexpr (MODE == 2) {
        f16* yb = (f16*)C0;
        const int b = bh >> 3, h = bh & 7;
#pragma unroll
        for (int mf = 0; mf < 8; ++mf) {
            int c0 = tm + (mf >> 2) * 128 + wr * 64 + (mf & 3) * 16 + (lane >> 4) * 4;
#pragma unroll
            for (int nf = 0; nf < 4; ++nf) {
                int l = tn + (nf >> 1) * 128 + wc * 32 + (nf & 1) * 16 + (lane & 15);
                size_t tok = (size_t)b * 4096 + (size_t)l * 8 + h;
                *(f16x4*)(yb + tok * 512 + c0) = cvt4(acc[mf][nf]);
            }
        }
    } else {
        float* O = (float*)C0;
#pragma unroll
        for (int mf = 0; mf < 8; ++mf) {
            int m = tm + (mf >> 2) * 128 + wr * 64 + (mf & 3) * 16 + (lane & 15);
#pragma unroll
            for (int nf = 0; nf < 4; ++nf) {
                int n0 = tn + (nf >> 1) * 128 + wc * 32 + (nf & 1) * 16 + (lane >> 4) * 4;
                float4 bv = *(const float4*)(bias + n0);
                f32x4 v = acc[mf][nf];
                v[0] += bv.x; v[1] += bv.y; v[2] += bv.z; v[3] += bv.w;
                *(f32x4*)(O + (size_t)m * 512 + n0) = v;
            }
        }
    }
}

// ---------------- softmax over 512-wide rows (wave per row, f16 in/out) -------
__global__ __launch_bounds__(256) void softmax_k(const f16* __restrict__ S,
                                                 f16* __restrict__ P) {
    int row = blockIdx.x * 4 + (threadIdx.x >> 6);
    int lane = threadIdx.x & 63;
    f16x8 v = *(const f16x8*)(S + (size_t)row * 512 + lane * 8);
    float f[8];
#pragma unroll
    for (int i = 0; i < 8; ++i) f[i] = (float)v[i];
    float m = f[0];
#pragma unroll
    for (int i = 1; i < 8; ++i) m = fmaxf(m, f[i]);
#pragma unroll
    for (int off = 1; off < 64; off <<= 1) m = fmaxf(m, __shfl_xor(m, off, 64));
    float s = 0.f, e[8];
#pragma unroll
    for (int i = 0; i < 8; ++i) { e[i] = __expf(f[i] - m); s += e[i]; }
#pragma unroll
    for (int off = 1; off < 64; off <<= 1) s += __shfl_xor(s, off, 64);
    float inv = 1.0f / s;
    f16x8 pk;
#pragma unroll
    for (int i = 0; i < 8; ++i) pk[i] = (f16)(e[i] * inv);
    *(f16x8*)(P + (size_t)row * 512 + lane * 8) = pk;
}

// ---------------- launch ------------------------------------------------------
extern "C" void kernel_launch(void* const* d_in, const int* in_sizes, int n_in,
                              void* d_out, int out_size, void* d_ws, size_t ws_size,
                              hipStream_t stream) {
    const float* x = (const float*)d_in[0];
    const float* wqkv = (const float*)d_in[1];
    const float* wout = (const float*)d_in[2];
    const float* bout = (const float*)d_in[3];
    float* out = (float*)d_out;
    char* ws = (char*)d_ws;
    const size_t MBs = 1u << 20;

    f16* xb  = (f16*)(ws + 0);            // 32MB
    f16* wqb = (f16*)(ws + 32 * MBs);     // 1.5MB
    f16* wob = (f16*)(ws + 34 * MBs);     // 0.5MB
    f16* Qb  = (f16*)(ws + 35 * MBs);     // 32MB
    f16* Kb  = (f16*)(ws + 67 * MBs);     // 32MB
    f16* Vb  = (f16*)(ws + 99 * MBs);     // 32MB
    f16* Sb  = (f16*)(ws + 131 * MBs);    // 32MB (f16 now, total 163MB)
    f16* Pb  = xb;                        // alias: xb dead after qkv GEMM
    f16* yb  = Qb;                        // alias: Q dead after S GEMM

    prep_k<<<1024, 256, 0, stream>>>(x, wqkv, wout, xb, wqb, wob);
    g8_k<0><<<768, 512, 0, stream>>>(xb, wqb, Qb, Kb, Vb, nullptr);
    g8_k<1><<<256, 512, 0, stream>>>(Qb, Kb, Sb, nullptr, nullptr, nullptr);
    softmax_k<<<8192, 256, 0, stream>>>(Sb, Pb);
    g8_k<2><<<256, 512, 0, stream>>>(Pb, Vb, yb, nullptr, nullptr, nullptr);
    g8_k<3><<<256, 512, 0, stream>>>(yb, wob, out, nullptr, nullptr, bout);
}

// Round 4
// 385.029 us; speedup vs baseline: 1.0934x; 1.0934x over previous
//
#include <hip/hip_runtime.h>
#include <stdint.h>
#include <stddef.h>

typedef _Float16 f16;
typedef _Float16 f16x8 __attribute__((ext_vector_type(8)));
typedef _Float16 f16x4 __attribute__((ext_vector_type(4)));
typedef float f32x4 __attribute__((ext_vector_type(4)));

__device__ __forceinline__ void gload16(const void* g, void* l) {
    auto gp = (const __attribute__((address_space(1))) uint32_t*)(uintptr_t)g;
    auto lp = (__attribute__((address_space(3))) uint32_t*)(uintptr_t)l;
    __builtin_amdgcn_global_load_lds(gp, lp, 16, 0, 0);
}

__device__ __forceinline__ f16x4 cvt4(f32x4 v) {
    return f16x4{ (f16)v[0], (f16)v[1], (f16)v[2], (f16)v[3] };
}

// ---------------- prep: f32 -> f16 conversions --------------------------------
__global__ __launch_bounds__(256) void prep_k(const float* __restrict__ x,
                                              const float* __restrict__ wqkv,
                                              const float* __restrict__ wout,
                                              f16* __restrict__ xb,
                                              f16* __restrict__ wqb,
                                              f16* __restrict__ wob) {
    int tid = blockIdx.x * blockDim.x + threadIdx.x;
    int stride = gridDim.x * blockDim.x;
    for (int i = tid; i < 4194304; i += stride) {
        float4 v = ((const float4*)x)[i];
        *(f16x4*)(xb + (size_t)i * 4) = f16x4{ (f16)v.x, (f16)v.y, (f16)v.z, (f16)v.w };
    }
    for (int i = tid; i < 196608; i += stride) {
        float4 v = ((const float4*)wqkv)[i];
        *(f16x4*)(wqb + (size_t)i * 4) = f16x4{ (f16)v.x, (f16)v.y, (f16)v.z, (f16)v.w };
    }
    for (int i = tid; i < 65536; i += stride) {
        float4 v = ((const float4*)wout)[i];
        *(f16x4*)(wob + (size_t)i * 4) = f16x4{ (f16)v.x, (f16)v.y, (f16)v.z, (f16)v.w };
    }
}

// ---------------- 256x256 tile, BK=64, 8-wave read-ahead pipelined GEMM -------
// C[m][n] = sum_k A[m][k]*B[n][k], K=512 (8 K-tiles of BK=64), row stride 512.
// Per K-tile (1 barrier, 1 vmcnt):
//   P0: issue bf1 reads; issue ALL 8 stage loads (tile t+1 -> buf NB); MFMA(afA,bf0)
//   P1: issue afB reads;                                               MFMA(afA,bf1)
//   P2:                                                                MFMA(afB,bf1)
//   P3: vmcnt(0); barrier; issue afA reads (buf NB); MFMA(afB,bf0); issue bf0 reads (NB)
// Reads for phase p+1 drain in the LDS pipe underneath phase p's MFMA cluster.
// Register budget (launch_bounds(512) -> 256 VGPR): acc 128 + frags 96 + offs 13.

#define MFMA_Q(MH, NH, AF, BF) do {                                             \
    __builtin_amdgcn_s_setprio(1);                                              \
    if (swp) {                                                                  \
        _Pragma("unroll") for (int kk = 0; kk < 2; ++kk)                        \
        _Pragma("unroll") for (int mi = 0; mi < 4; ++mi)                        \
        _Pragma("unroll") for (int ni = 0; ni < 2; ++ni)                        \
            acc[(MH)*4+mi][(NH)*2+ni] = __builtin_amdgcn_mfma_f32_16x16x32_f16( \
                BF[ni][kk], AF[mi][kk], acc[(MH)*4+mi][(NH)*2+ni], 0, 0, 0);    \
    } else {                                                                    \
        _Pragma("unroll") for (int kk = 0; kk < 2; ++kk)                        \
        _Pragma("unroll") for (int mi = 0; mi < 4; ++mi)                        \
        _Pragma("unroll") for (int ni = 0; ni < 2; ++ni)                        \
            acc[(MH)*4+mi][(NH)*2+ni] = __builtin_amdgcn_mfma_f32_16x16x32_f16( \
                AF[mi][kk], BF[ni][kk], acc[(MH)*4+mi][(NH)*2+ni], 0, 0, 0);    \
    }                                                                           \
    __builtin_amdgcn_s_setprio(0);                                              \
} while (0)

// mh=1 / nh=1 fragment rows are +128 rows; s(r+128)==s(r), so offset = base + 8192 f16.
#define RD_AFA(LA) do { _Pragma("unroll") for (int mi = 0; mi < 4; ++mi)        \
    _Pragma("unroll") for (int kk = 0; kk < 2; ++kk)                            \
        afA[mi][kk] = *(const f16x8*)((LA) + aoffA[mi][kk]); } while (0)
#define RD_AFB(LA) do { _Pragma("unroll") for (int mi = 0; mi < 4; ++mi)        \
    _Pragma("unroll") for (int kk = 0; kk < 2; ++kk)                            \
        afB[mi][kk] = *(const f16x8*)((LA) + aoffA[mi][kk] + 8192); } while (0)
#define RD_BF0(LB) do { _Pragma("unroll") for (int ni = 0; ni < 2; ++ni)        \
    _Pragma("unroll") for (int kk = 0; kk < 2; ++kk)                            \
        bf0[ni][kk] = *(const f16x8*)((LB) + boff0[ni][kk]); } while (0)
#define RD_BF1(LB) do { _Pragma("unroll") for (int ni = 0; ni < 2; ++ni)        \
    _Pragma("unroll") for (int kk = 0; kk < 2; ++kk)                            \
        bf1[ni][kk] = *(const f16x8*)((LB) + boff0[ni][kk] + 8192); } while (0)

// staging: single per-lane byte offset soff, uniform bases, constant chunk offsets
#define STAGE_A(h, li, NB) gload16(Ab + kb + soff + ((h)*131072 + (li)*65536),  \
    &lds[NB][0][((h)*128+(li)*64+wid*8)*64])
#define STAGE_B(h, li, NB) gload16(Bb + kb + soff + ((h)*131072 + (li)*65536),  \
    &lds[NB][1][((h)*128+(li)*64+wid*8)*64])
#define STAGE_ALL(NB) do {                                                      \
    STAGE_A(0,0,NB); STAGE_A(0,1,NB); STAGE_B(0,0,NB); STAGE_B(0,1,NB);         \
    STAGE_B(1,0,NB); STAGE_B(1,1,NB); STAGE_A(1,0,NB); STAGE_A(1,1,NB); } while (0)

#define TILE(CB, NB, STG, FINAL) do {                                           \
    RD_BF1(&lds[CB][1][0]);                                                     \
    if (STG) { STAGE_ALL(NB); kb += 128; }                                      \
    MFMA_Q(0, 0, afA, bf0);                                                     \
    RD_AFB(&lds[CB][0][0]);                                                     \
    MFMA_Q(0, 1, afA, bf1);                                                     \
    MFMA_Q(1, 1, afB, bf1);                                                     \
    if (!FINAL) {                                                               \
        asm volatile("s_waitcnt vmcnt(0)" ::: "memory");                        \
        __builtin_amdgcn_s_barrier();                                           \
        RD_AFA(&lds[NB][0][0]);                                                 \
    }                                                                           \
    MFMA_Q(1, 0, afB, bf0);                                                     \
    if (!FINAL) RD_BF0(&lds[NB][1][0]);                                         \
} while (0)

template <int MODE>
__global__ __launch_bounds__(512) void g8_k(const f16* __restrict__ A0,
                                            const f16* __restrict__ B0,
                                            void* __restrict__ C0,
                                            void* __restrict__ C1,
                                            void* __restrict__ C2,
                                            const float* __restrict__ bias) {
    __shared__ f16 lds[2][2][16384];   // [buf][A/B][256 rows x 64 k], 128 KiB

    const int tid = threadIdx.x;
    const int lane = tid & 63;
    const int wid = tid >> 6;
    const int wr = wid >> 2;   // 0..1
    const int wc = wid & 3;    // 0..3

    int tm, tn, bh = 0;
    bool qk = false, swp;
    const int bid = blockIdx.x;
    if constexpr (MODE == 0) {
        int swz = (bid & 7) * 96 + (bid >> 3);          // 768 blocks, bijective
        tm = (swz / 6) * 256; tn = (swz % 6) * 256;
        qk = tn < 1024; swp = !qk;
    } else if constexpr (MODE == 1 || MODE == 2) {
        int swz = (bid & 7) * 32 + (bid >> 3);          // 256 blocks
        bh = swz >> 2; tm = ((swz >> 1) & 1) * 256; tn = (swz & 1) * 256;
        swp = (MODE == 1);
    } else {
        int swz = (bid & 7) * 32 + (bid >> 3);          // 256 blocks
        tm = (swz >> 1) * 256; tn = (swz & 1) * 256;
        swp = true;
    }

    const size_t bhoff = (MODE == 1 || MODE == 2) ? (size_t)bh * 262144 : 0;
    const char* Ab = (const char*)(A0 + bhoff + (size_t)tm * 512);
    const char* Bb = (const char*)(B0 + bhoff + (size_t)tn * 512);

    // staging swizzle: chunk c8 = (tid&7) ^ s(r); s(r) = ((tid>>3)&7) ^ wid
    // for every chunk this block stages -> ONE per-lane byte offset.
    const int c8s = (tid & 7) ^ (((tid >> 3) & 7) ^ wid);
    const int soff = (tid >> 3) * 1024 + c8s * 16;
    int kb = 0;

    // fragment LDS offsets (f16 units), swizzled reads; mh=0/nh=0 only
    int aoffA[4][2], boff0[2][2];
#pragma unroll
    for (int mi = 0; mi < 4; ++mi) {
        int r = qk ? ((lane & 15) * 8 + wr * 4 + mi)
                   : (wr * 64 + mi * 16 + (lane & 15));
#pragma unroll
        for (int kk = 0; kk < 2; ++kk) {
            int c8 = (lane >> 4) + kk * 4;
            aoffA[mi][kk] = r * 64 + (c8 ^ ((r & 7) ^ ((r >> 3) & 7))) * 8;
        }
    }
#pragma unroll
    for (int ni = 0; ni < 2; ++ni) {
        int r = wc * 32 + ni * 16 + (lane & 15);
#pragma unroll
        for (int kk = 0; kk < 2; ++kk) {
            int c8 = (lane >> 4) + kk * 4;
            boff0[ni][kk] = r * 64 + (c8 ^ ((r & 7) ^ ((r >> 3) & 7))) * 8;
        }
    }

    f32x4 acc[8][4] = {};
    f16x8 afA[4][2], afB[4][2], bf0[2][2], bf1[2][2];

    // ---- prologue: stage tile 0, drain, pre-issue afA/bf0 reads
    STAGE_ALL(0);
    kb += 128;
    asm volatile("s_waitcnt vmcnt(0)" ::: "memory");
    __builtin_amdgcn_s_barrier();
    RD_AFA(&lds[0][0][0]);
    RD_BF0(&lds[0][1][0]);

    // ---- main: tiles 0..6 staged pairs, t7 final
#pragma unroll 1
    for (int i = 0; i < 3; ++i) {
        TILE(0, 1, true, false);
        TILE(1, 0, true, false);
    }
    TILE(0, 1, true, false);
    TILE(1, 0, false, true);

    // ---------------- epilogues ----------------
    if constexpr (MODE == 0) {
        const int b = tm >> 12;
        if (qk) {
            f16* dst = (f16*)(tn < 512 ? C0 : C1);
            const int lt = (tm & 4095) >> 3;
            const int cb = (tn & 511) + wc * 32;
#pragma unroll
            for (int mf = 0; mf < 8; ++mf) {
                int h = wr * 4 + (mf & 3);
                int lh0 = lt + (mf >> 2) * 16 + (lane >> 4) * 4;
#pragma unroll
                for (int nf = 0; nf < 4; ++nf) {
                    int c = cb + (nf >> 1) * 128 + (nf & 1) * 16 + (lane & 15);
                    *(f16x4*)(dst + ((size_t)((b * 8 + h) * 512 + c)) * 512 + lh0) =
                        cvt4(acc[mf][nf]);
                }
            }
        } else {
            f16* dst = (f16*)C2;
#pragma unroll
            for (int mf = 0; mf < 8; ++mf) {
                int m = (tm & 4095) + (mf >> 2) * 128 + wr * 64 + (mf & 3) * 16 + (lane & 15);
                int h = m & 7;
                int lh = m >> 3;
#pragma unroll
                for (int nf = 0; nf < 4; ++nf) {
                    int d0 = (tn - 1024) + (nf >> 1) * 128 + wc * 32 + (nf & 1) * 16 + (lane >> 4) * 4;
                    *(f16x4*)(dst + ((size_t)((b * 8 + h) * 512 + lh)) * 512 + d0) =
                        cvt4(acc[mf][nf]);
                }
            }
        }
    } else if constexpr (MODE == 1) {
        f16* S = (f16*)C0 + (size_t)bh * 262144;
#pragma unroll
        for (int mf = 0; mf < 8; ++mf) {
            int cm = tm + (mf >> 2) * 128 + wr * 64 + (mf & 3) * 16 + (lane & 15);
#pragma unroll
            for (int nf = 0; nf < 4; ++nf) {
                int d0 = tn + (nf >> 1) * 128 + wc * 32 + (nf & 1) * 16 + (lane >> 4) * 4;
                *(f16x4*)(S + (size_t)cm * 512 + d0) = cvt4(acc[mf][nf] * 0.125f);
            }
        }
    } else if constexpr (MODE == 2) {
        f16* yb = (f16*)C0;
        const int b = bh >> 3, h = bh & 7;
#pragma unroll
        for (int mf = 0; mf < 8; ++mf) {
            int c0 = tm + (mf >> 2) * 128 + wr * 64 + (mf & 3) * 16 + (lane >> 4) * 4;
#pragma unroll
            for (int nf = 0; nf < 4; ++nf) {
                int l = tn + (nf >> 1) * 128 + wc * 32 + (nf & 1) * 16 + (lane & 15);
                size_t tok = (size_t)b * 4096 + (size_t)l * 8 + h;
                *(f16x4*)(yb + tok * 512 + c0) = cvt4(acc[mf][nf]);
            }
        }
    } else {
        float* O = (float*)C0;
#pragma unroll
        for (int mf = 0; mf < 8; ++mf) {
            int m = tm + (mf >> 2) * 128 + wr * 64 + (mf & 3) * 16 + (lane & 15);
#pragma unroll
            for (int nf = 0; nf < 4; ++nf) {
                int n0 = tn + (nf >> 1) * 128 + wc * 32 + (nf & 1) * 16 + (lane >> 4) * 4;
                float4 bv = *(const float4*)(bias + n0);
                f32x4 v = acc[mf][nf];
                v[0] += bv.x; v[1] += bv.y; v[2] += bv.z; v[3] += bv.w;
                *(f32x4*)(O + (size_t)m * 512 + n0) = v;
            }
        }
    }
}

// ---------------- softmax over 512-wide rows (wave per row, f16 in/out) -------
__global__ __launch_bounds__(256) void softmax_k(const f16* __restrict__ S,
                                                 f16* __restrict__ P) {
    int row = blockIdx.x * 4 + (threadIdx.x >> 6);
    int lane = threadIdx.x & 63;
    f16x8 v = *(const f16x8*)(S + (size_t)row * 512 + lane * 8);
    float f[8];
#pragma unroll
    for (int i = 0; i < 8; ++i) f[i] = (float)v[i];
    float m = f[0];
#pragma unroll
    for (int i = 1; i < 8; ++i) m = fmaxf(m, f[i]);
#pragma unroll
    for (int off = 1; off < 64; off <<= 1) m = fmaxf(m, __shfl_xor(m, off, 64));
    float s = 0.f, e[8];
#pragma unroll
    for (int i = 0; i < 8; ++i) { e[i] = __expf(f[i] - m); s += e[i]; }
#pragma unroll
    for (int off = 1; off < 64; off <<= 1) s += __shfl_xor(s, off, 64);
    float inv = 1.0f / s;
    f16x8 pk;
#pragma unroll
    for (int i = 0; i < 8; ++i) pk[i] = (f16)(e[i] * inv);
    *(f16x8*)(P + (size_t)row * 512 + lane * 8) = pk;
}

// ---------------- launch ------------------------------------------------------
extern "C" void kernel_launch(void* const* d_in, const int* in_sizes, int n_in,
                              void* d_out, int out_size, void* d_ws, size_t ws_size,
                              hipStream_t stream) {
    const float* x = (const float*)d_in[0];
    const float* wqkv = (const float*)d_in[1];
    const float* wout = (const float*)d_in[2];
    const float* bout = (const float*)d_in[3];
    float* out = (float*)d_out;
    char* ws = (char*)d_ws;
    const size_t MBs = 1u << 20;

    f16* xb  = (f16*)(ws + 0);            // 32MB
    f16* wqb = (f16*)(ws + 32 * MBs);     // 1.5MB
    f16* wob = (f16*)(ws + 34 * MBs);     // 0.5MB
    f16* Qb  = (f16*)(ws + 35 * MBs);     // 32MB
    f16* Kb  = (f16*)(ws + 67 * MBs);     // 32MB
    f16* Vb  = (f16*)(ws + 99 * MBs);     // 32MB
    f16* Sb  = (f16*)(ws + 131 * MBs);    // 32MB (total 163MB)
    f16* Pb  = xb;                        // alias: xb dead after qkv GEMM
    f16* yb  = Qb;                        // alias: Q dead after S GEMM

    prep_k<<<1024, 256, 0, stream>>>(x, wqkv, wout, xb, wqb, wob);
    g8_k<0><<<768, 512, 0, stream>>>(xb, wqb, Qb, Kb, Vb, nullptr);
    g8_k<1><<<256, 512, 0, stream>>>(Qb, Kb, Sb, nullptr, nullptr, nullptr);
    softmax_k<<<8192, 256, 0, stream>>>(Sb, Pb);
    g8_k<2><<<256, 512, 0, stream>>>(Pb, Vb, yb, nullptr, nullptr, nullptr);
    g8_k<3><<<256, 512, 0, stream>>>(yb, wob, out, nullptr, nullptr, bout);
}

// Round 5
// 201.339 us; speedup vs baseline: 2.0910x; 1.9123x over previous
//
#include <hip/hip_runtime.h>
#include <stdint.h>
#include <stddef.h>

typedef _Float16 f16;
typedef _Float16 f16x8 __attribute__((ext_vector_type(8)));
typedef _Float16 f16x4 __attribute__((ext_vector_type(4)));
typedef float f32x4 __attribute__((ext_vector_type(4)));

__device__ __forceinline__ void gload16(const void* g, void* l) {
    auto gp = (const __attribute__((address_space(1))) uint32_t*)(uintptr_t)g;
    auto lp = (__attribute__((address_space(3))) uint32_t*)(uintptr_t)l;
    __builtin_amdgcn_global_load_lds(gp, lp, 16, 0, 0);
}

__device__ __forceinline__ f16x4 cvt4(f32x4 v) {
    return f16x4{ (f16)v[0], (f16)v[1], (f16)v[2], (f16)v[3] };
}

// ---------------- prep: f32 -> f16 conversions --------------------------------
__global__ __launch_bounds__(256) void prep_k(const float* __restrict__ x,
                                              const float* __restrict__ wqkv,
                                              const float* __restrict__ wout,
                                              f16* __restrict__ xb,
                                              f16* __restrict__ wqb,
                                              f16* __restrict__ wob) {
    int tid = blockIdx.x * blockDim.x + threadIdx.x;
    int stride = gridDim.x * blockDim.x;
    for (int i = tid; i < 4194304; i += stride) {
        float4 v = ((const float4*)x)[i];
        *(f16x4*)(xb + (size_t)i * 4) = f16x4{ (f16)v.x, (f16)v.y, (f16)v.z, (f16)v.w };
    }
    for (int i = tid; i < 196608; i += stride) {
        float4 v = ((const float4*)wqkv)[i];
        *(f16x4*)(wqb + (size_t)i * 4) = f16x4{ (f16)v.x, (f16)v.y, (f16)v.z, (f16)v.w };
    }
    for (int i = tid; i < 65536; i += stride) {
        float4 v = ((const float4*)wout)[i];
        *(f16x4*)(wob + (size_t)i * 4) = f16x4{ (f16)v.x, (f16)v.y, (f16)v.z, (f16)v.w };
    }
}

// ---------------- 256x128 tile, BK=64, triple-buffered read-ahead GEMM --------
// C[m][n] = sum_k A[m][k]*B[n][k], K=512, row stride 512 f16.
// 8 waves: wr = wid>>1 (4 M-strips of 64), wc = wid&1 (2 N-strips of 64).
// Per wave: acc[4][4] f32x4 = 64 regs (AGPR) -> 192 arch VGPRs available.
// K-loop fully unrolled, 3 LDS buffers, stage 2 tiles ahead, vmcnt(6) counted,
// one barrier per K-tile; next-tile fragments ds_read right after the barrier,
// drain under the last MFMA cluster + next tile's first clusters.

#define STAGE(SB) do {                                                          \
    gload16(Ab + kb + soff,          &ldsA[SB][( 0 + wid*8)*64]);               \
    gload16(Ab + kb + soff + 65536,  &ldsA[SB][( 64 + wid*8)*64]);              \
    gload16(Ab + kb + soff + 131072, &ldsA[SB][(128 + wid*8)*64]);              \
    gload16(Ab + kb + soff + 196608, &ldsA[SB][(192 + wid*8)*64]);              \
    gload16(Bb + kb + soff,          &ldsB[SB][( 0 + wid*8)*64]);               \
    gload16(Bb + kb + soff + 65536,  &ldsB[SB][( 64 + wid*8)*64]);              \
    kb += 128;                                                                  \
} while (0)

#define RD(SET, BUF) do {                                                       \
    _Pragma("unroll") for (int mi = 0; mi < 4; ++mi)                            \
    _Pragma("unroll") for (int kk = 0; kk < 2; ++kk)                            \
        aF##SET[mi][kk] = *(const f16x8*)(&ldsA[BUF][0] + aoff[mi][kk]);        \
    _Pragma("unroll") for (int ni = 0; ni < 4; ++ni)                            \
    _Pragma("unroll") for (int kk = 0; kk < 2; ++kk)                            \
        bF##SET[ni][kk] = *(const f16x8*)(&ldsB[BUF][0] + boff[ni][kk]);        \
} while (0)

#define MM(SET, KK, ML, MH_) do {                                               \
    __builtin_amdgcn_s_setprio(1);                                              \
    _Pragma("unroll") for (int mi = ML; mi < MH_; ++mi)                         \
    _Pragma("unroll") for (int ni = 0; ni < 4; ++ni) {                          \
        if constexpr (SWP)                                                      \
            acc[mi][ni] = __builtin_amdgcn_mfma_f32_16x16x32_f16(               \
                bF##SET[ni][KK], aF##SET[mi][KK], acc[mi][ni], 0, 0, 0);        \
        else                                                                    \
            acc[mi][ni] = __builtin_amdgcn_mfma_f32_16x16x32_f16(               \
                aF##SET[mi][KK], bF##SET[ni][KK], acc[mi][ni], 0, 0, 0);        \
    }                                                                           \
    __builtin_amdgcn_s_setprio(0);                                              \
} while (0)

#define MM3(SET)   do { MM(SET, 0, 0, 2); MM(SET, 0, 2, 4); MM(SET, 1, 0, 2); } while (0)
#define MMLAST(SET) MM(SET, 1, 2, 4)
#define W6  asm volatile("s_waitcnt vmcnt(6)" ::: "memory")
#define W0  asm volatile("s_waitcnt vmcnt(0)" ::: "memory")
#define BAR __builtin_amdgcn_s_barrier()

// MODE 0 + QK:  qkv Q/K part (normal mfma, permuted A rows) -> Q/K [bh][c][lh]
// MODE 0 + SWP: qkv V part   (swapped)                      -> V   [bh][lh][d]
// MODE 1: S = Q K^T * 0.125 per bh (swapped, f16 out)
// MODE 2: Y = P V per bh (normal, f16 out to y[token][c])
// MODE 3: out = y w_out^T + b_out (swapped, f32 out)
template <int MODE, bool SWP, bool QK>
__global__ __launch_bounds__(512) void g9_k(const f16* __restrict__ A0,
                                            const f16* __restrict__ B0,
                                            void* __restrict__ C0,
                                            void* __restrict__ C1,
                                            const float* __restrict__ bias) {
    __shared__ f16 ldsA[3][16384];   // 3 x 256x64, 96 KiB
    __shared__ f16 ldsB[3][8192];    // 3 x 128x64, 48 KiB

    const int tid = threadIdx.x;
    const int lane = tid & 63;
    const int wid = tid >> 6;
    const int wr = wid >> 1;   // 0..3  (M strip of 64)
    const int wc = wid & 1;    // 0..1  (N strip of 64)

    const int bid = blockIdx.x;
    int tm, tn, bh = 0;
    if constexpr (MODE == 0 && QK) {
        int swz = (bid & 7) * 128 + (bid >> 3);       // 1024 blocks
        tm = (swz >> 3) * 256; tn = (swz & 7) * 128;
    } else if constexpr (MODE == 0) {
        int swz = (bid & 7) * 64 + (bid >> 3);        // 512 blocks
        tm = (swz >> 2) * 256; tn = (swz & 3) * 128;
    } else if constexpr (MODE == 1 || MODE == 2) {
        int swz = (bid & 7) * 64 + (bid >> 3);        // 512 blocks
        bh = swz >> 3; tm = ((swz >> 2) & 1) * 256; tn = (swz & 3) * 128;
    } else {
        int swz = (bid & 7) * 64 + (bid >> 3);        // 512 blocks
        tm = (swz >> 2) * 256; tn = (swz & 3) * 128;
    }

    const size_t bhoff = (MODE == 1 || MODE == 2) ? (size_t)bh * 262144 : 0;
    const char* Ab = (const char*)(A0 + bhoff + (size_t)tm * 512);
    const char* Bb = (const char*)(B0 + bhoff + (size_t)tn * 512);

    // staging: chunk c8 = (tid&7) ^ s(r); for all staged chunks s(r) = ((tid>>3)&7)^wid
    const int c8s = (tid & 7) ^ (((tid >> 3) & 7) ^ wid);
    const int soff = (tid >> 3) * 1024 + c8s * 16;
    int kb = 0;

    // fragment LDS offsets (f16 units), swizzled: off = r*64 + (c8 ^ s(r))*8
    int aoff[4][2], boff[4][2];
#pragma unroll
    for (int mi = 0; mi < 4; ++mi) {
        int r;
        if constexpr (QK) {
            int e = wr * 4 + mi;                       // 0..15
            r = (lane & 15) * 8 + (e >> 3) * 128 + (e & 7);
        } else {
            r = wr * 64 + mi * 16 + (lane & 15);
        }
#pragma unroll
        for (int kk = 0; kk < 2; ++kk) {
            int c8 = (lane >> 4) + kk * 4;
            aoff[mi][kk] = r * 64 + (c8 ^ ((r & 7) ^ ((r >> 3) & 7))) * 8;
        }
    }
#pragma unroll
    for (int ni = 0; ni < 4; ++ni) {
        int r = wc * 64 + ni * 16 + (lane & 15);
#pragma unroll
        for (int kk = 0; kk < 2; ++kk) {
            int c8 = (lane >> 4) + kk * 4;
            boff[ni][kk] = r * 64 + (c8 ^ ((r & 7) ^ ((r >> 3) & 7))) * 8;
        }
    }

    f32x4 acc[4][4] = {};
    f16x8 aF0[4][2], bF0[4][2], aF1[4][2], bF1[4][2];

    // prologue: stage tiles 0,1 -> bufs 0,1; wait tile0; read set0
    STAGE(0); STAGE(1);
    W6; BAR;
    RD(0, 0);

    // fully unrolled K-loop: stage (t+2)%3, wait (t-1) done, read (t+1)%3
    STAGE(2); MM3(0); W6; BAR; RD(1, 1); MMLAST(0);   // t0
    STAGE(0); MM3(1); W6; BAR; RD(0, 2); MMLAST(1);   // t1
    STAGE(1); MM3(0); W6; BAR; RD(1, 0); MMLAST(0);   // t2
    STAGE(2); MM3(1); W6; BAR; RD(0, 1); MMLAST(1);   // t3
    STAGE(0); MM3(0); W6; BAR; RD(1, 2); MMLAST(0);   // t4
    STAGE(1); MM3(1); W6; BAR; RD(0, 0); MMLAST(1);   // t5
              MM3(0); W0; BAR; RD(1, 1); MMLAST(0);   // t6
              MM3(1);                    MMLAST(1);   // t7

    // ---------------- epilogues ----------------
    if constexpr (MODE == 0 && QK) {
        const int b = tm >> 12;
        const int lt = (tm & 4095) >> 3;
        f16* dst = (f16*)(tn < 512 ? C0 : C1);
        const int cb = (tn & 511) + wc * 64;
#pragma unroll
        for (int mi = 0; mi < 4; ++mi) {
            int e = wr * 4 + mi;
            int h = e & 7;
            int lh0 = lt + (e >> 3) * 16 + (lane >> 4) * 4;
#pragma unroll
            for (int ni = 0; ni < 4; ++ni) {
                int c = cb + ni * 16 + (lane & 15);
                *(f16x4*)(dst + ((size_t)((b * 8 + h) * 512 + c)) * 512 + lh0) =
                    cvt4(acc[mi][ni]);
            }
        }
    } else if constexpr (MODE == 0) {      // V, swapped
        f16* dst = (f16*)C0;
#pragma unroll
        for (int mi = 0; mi < 4; ++mi) {
            int t = tm + wr * 64 + mi * 16 + (lane & 15);
            int b = t >> 12, l = t & 4095;
            int h = l & 7, lh = l >> 3;
#pragma unroll
            for (int ni = 0; ni < 4; ++ni) {
                int d0 = tn + wc * 64 + ni * 16 + (lane >> 4) * 4;
                *(f16x4*)(dst + ((size_t)((b * 8 + h) * 512 + lh)) * 512 + d0) =
                    cvt4(acc[mi][ni]);
            }
        }
    } else if constexpr (MODE == 1) {
        f16* S = (f16*)C0 + (size_t)bh * 262144;
#pragma unroll
        for (int mi = 0; mi < 4; ++mi) {
            int cm = tm + wr * 64 + mi * 16 + (lane & 15);
#pragma unroll
            for (int ni = 0; ni < 4; ++ni) {
                int d0 = tn + wc * 64 + ni * 16 + (lane >> 4) * 4;
                *(f16x4*)(S + (size_t)cm * 512 + d0) = cvt4(acc[mi][ni] * 0.125f);
            }
        }
    } else if constexpr (MODE == 2) {
        f16* yb = (f16*)C0;
        const int b = bh >> 3, h = bh & 7;
#pragma unroll
        for (int mi = 0; mi < 4; ++mi) {
            int c0 = tm + wr * 64 + mi * 16 + (lane >> 4) * 4;
#pragma unroll
            for (int ni = 0; ni < 4; ++ni) {
                int l = tn + wc * 64 + ni * 16 + (lane & 15);
                size_t tok = (size_t)b * 4096 + (size_t)l * 8 + h;
                *(f16x4*)(yb + tok * 512 + c0) = cvt4(acc[mi][ni]);
            }
        }
    } else {
        float* O = (float*)C0;
#pragma unroll
        for (int mi = 0; mi < 4; ++mi) {
            int m = tm + wr * 64 + mi * 16 + (lane & 15);
#pragma unroll
            for (int ni = 0; ni < 4; ++ni) {
                int n0 = tn + wc * 64 + ni * 16 + (lane >> 4) * 4;
                float4 bv = *(const float4*)(bias + n0);
                f32x4 v = acc[mi][ni];
                v[0] += bv.x; v[1] += bv.y; v[2] += bv.z; v[3] += bv.w;
                *(f32x4*)(O + (size_t)m * 512 + n0) = v;
            }
        }
    }
}

// ---------------- softmax over 512-wide rows (wave per row, f16 in/out) -------
__global__ __launch_bounds__(256) void softmax_k(const f16* __restrict__ S,
                                                 f16* __restrict__ P) {
    int row = blockIdx.x * 4 + (threadIdx.x >> 6);
    int lane = threadIdx.x & 63;
    f16x8 v = *(const f16x8*)(S + (size_t)row * 512 + lane * 8);
    float f[8];
#pragma unroll
    for (int i = 0; i < 8; ++i) f[i] = (float)v[i];
    float m = f[0];
#pragma unroll
    for (int i = 1; i < 8; ++i) m = fmaxf(m, f[i]);
#pragma unroll
    for (int off = 1; off < 64; off <<= 1) m = fmaxf(m, __shfl_xor(m, off, 64));
    float s = 0.f, e[8];
#pragma unroll
    for (int i = 0; i < 8; ++i) { e[i] = __expf(f[i] - m); s += e[i]; }
#pragma unroll
    for (int off = 1; off < 64; off <<= 1) s += __shfl_xor(s, off, 64);
    float inv = 1.0f / s;
    f16x8 pk;
#pragma unroll
    for (int i = 0; i < 8; ++i) pk[i] = (f16)(e[i] * inv);
    *(f16x8*)(P + (size_t)row * 512 + lane * 8) = pk;
}

// ---------------- launch ------------------------------------------------------
extern "C" void kernel_launch(void* const* d_in, const int* in_sizes, int n_in,
                              void* d_out, int out_size, void* d_ws, size_t ws_size,
                              hipStream_t stream) {
    const float* x = (const float*)d_in[0];
    const float* wqkv = (const float*)d_in[1];
    const float* wout = (const float*)d_in[2];
    const float* bout = (const float*)d_in[3];
    float* out = (float*)d_out;
    char* ws = (char*)d_ws;
    const size_t MBs = 1u << 20;

    f16* xb  = (f16*)(ws + 0);            // 32MB
    f16* wqb = (f16*)(ws + 32 * MBs);     // 1.5MB
    f16* wob = (f16*)(ws + 34 * MBs);     // 0.5MB
    f16* Qb  = (f16*)(ws + 35 * MBs);     // 32MB
    f16* Kb  = (f16*)(ws + 67 * MBs);     // 32MB
    f16* Vb  = (f16*)(ws + 99 * MBs);     // 32MB
    f16* Sb  = (f16*)(ws + 131 * MBs);    // 32MB (total 163MB)
    f16* Pb  = xb;                        // alias: xb dead after qkv GEMM
    f16* yb  = Qb;                        // alias: Q dead after S GEMM

    prep_k<<<1024, 256, 0, stream>>>(x, wqkv, wout, xb, wqb, wob);
    g9_k<0, false, true><<<1024, 512, 0, stream>>>(xb, wqb, Qb, Kb, nullptr);
    g9_k<0, true, false><<<512, 512, 0, stream>>>(xb, wqb + (size_t)1024 * 512, Vb, nullptr, nullptr);
    g9_k<1, true, false><<<512, 512, 0, stream>>>(Qb, Kb, Sb, nullptr, nullptr);
    softmax_k<<<8192, 256, 0, stream>>>(Sb, Pb);
    g9_k<2, false, false><<<512, 512, 0, stream>>>(Pb, Vb, yb, nullptr, nullptr);
    g9_k<3, true, false><<<512, 512, 0, stream>>>(yb, wob, out, nullptr, bout);
}

// Round 6
// 198.279 us; speedup vs baseline: 2.1233x; 1.0154x over previous
//
#include <hip/hip_runtime.h>
#include <stdint.h>
#include <stddef.h>

typedef _Float16 f16;
typedef _Float16 f16x8 __attribute__((ext_vector_type(8)));
typedef _Float16 f16x4 __attribute__((ext_vector_type(4)));
typedef float f32x4 __attribute__((ext_vector_type(4)));

__device__ __forceinline__ void gload16(const void* g, void* l) {
    auto gp = (const __attribute__((address_space(1))) uint32_t*)(uintptr_t)g;
    auto lp = (__attribute__((address_space(3))) uint32_t*)(uintptr_t)l;
    __builtin_amdgcn_global_load_lds(gp, lp, 16, 0, 0);
}

__device__ __forceinline__ f16x4 cvt4(f32x4 v) {
    return f16x4{ (f16)v[0], (f16)v[1], (f16)v[2], (f16)v[3] };
}

// ---------------- prep: f32 -> f16 conversions --------------------------------
__global__ __launch_bounds__(256) void prep_k(const float* __restrict__ x,
                                              const float* __restrict__ wqkv,
                                              const float* __restrict__ wout,
                                              f16* __restrict__ xb,
                                              f16* __restrict__ wqb,
                                              f16* __restrict__ wob) {
    int tid = blockIdx.x * blockDim.x + threadIdx.x;
    int stride = gridDim.x * blockDim.x;
    for (int i = tid; i < 4194304; i += stride) {
        float4 v = ((const float4*)x)[i];
        *(f16x4*)(xb + (size_t)i * 4) = f16x4{ (f16)v.x, (f16)v.y, (f16)v.z, (f16)v.w };
    }
    for (int i = tid; i < 196608; i += stride) {
        float4 v = ((const float4*)wqkv)[i];
        *(f16x4*)(wqb + (size_t)i * 4) = f16x4{ (f16)v.x, (f16)v.y, (f16)v.z, (f16)v.w };
    }
    for (int i = tid; i < 65536; i += stride) {
        float4 v = ((const float4*)wout)[i];
        *(f16x4*)(wob + (size_t)i * 4) = f16x4{ (f16)v.x, (f16)v.y, (f16)v.z, (f16)v.w };
    }
}

// ---------------- 128x128 tile, BK=64, dbuf LDS, 2 blocks/CU GEMM -------------
// C[m][n] = sum_k A[m][k]*B[n][k], K=512, row stride 512 f16.
// 4 waves: wr = wid>>1 (2 M-strips of 64), wc = wid&1 (2 N-strips of 64).
// acc[4][4] = 64 AGPR; 64 KB LDS (2 bufs) -> 2 independent blocks/CU whose
// phase drift overlaps one block's barrier/lgkm drains with the other's MFMA.
// Per K-tile: STAGE(next->other buf); MM3(cur); vmcnt(0); barrier; RD(next);
// MMLAST(cur) — 1 barrier + 1 vmcnt per tile, reads drain under MMLAST.

#define STAGE(NB) do {                                                          \
    gload16(Ab + kb + sE,          &ldsA[NB][( 0 + wid*8)*64]);                 \
    gload16(Ab + kb + sO + 32768,  &ldsA[NB][(32 + wid*8)*64]);                 \
    gload16(Ab + kb + sE + 65536,  &ldsA[NB][(64 + wid*8)*64]);                 \
    gload16(Ab + kb + sO + 98304,  &ldsA[NB][(96 + wid*8)*64]);                 \
    gload16(Bb + kb + sE,          &ldsB[NB][( 0 + wid*8)*64]);                 \
    gload16(Bb + kb + sO + 32768,  &ldsB[NB][(32 + wid*8)*64]);                 \
    gload16(Bb + kb + sE + 65536,  &ldsB[NB][(64 + wid*8)*64]);                 \
    gload16(Bb + kb + sO + 98304,  &ldsB[NB][(96 + wid*8)*64]);                 \
    kb += 128;                                                                  \
} while (0)

#define RD(SET, BUF) do {                                                       \
    _Pragma("unroll") for (int mi = 0; mi < 4; ++mi)                            \
    _Pragma("unroll") for (int kk = 0; kk < 2; ++kk)                            \
        aF##SET[mi][kk] = *(const f16x8*)(&ldsA[BUF][0] + aoff[mi][kk]);        \
    _Pragma("unroll") for (int ni = 0; ni < 4; ++ni)                            \
    _Pragma("unroll") for (int kk = 0; kk < 2; ++kk)                            \
        bF##SET[ni][kk] = *(const f16x8*)(&ldsB[BUF][0] + boff[ni][kk]);        \
} while (0)

#define MM(SET, KK, ML, MH_) do {                                               \
    __builtin_amdgcn_s_setprio(1);                                              \
    _Pragma("unroll") for (int mi = ML; mi < MH_; ++mi)                         \
    _Pragma("unroll") for (int ni = 0; ni < 4; ++ni) {                          \
        if constexpr (SWP)                                                      \
            acc[mi][ni] = __builtin_amdgcn_mfma_f32_16x16x32_f16(               \
                bF##SET[ni][KK], aF##SET[mi][KK], acc[mi][ni], 0, 0, 0);        \
        else                                                                    \
            acc[mi][ni] = __builtin_amdgcn_mfma_f32_16x16x32_f16(               \
                aF##SET[mi][KK], bF##SET[ni][KK], acc[mi][ni], 0, 0, 0);        \
    }                                                                           \
    __builtin_amdgcn_s_setprio(0);                                              \
} while (0)

#define MM3(SET)   do { MM(SET, 0, 0, 2); MM(SET, 0, 2, 4); MM(SET, 1, 0, 2); } while (0)
#define MMLAST(SET) MM(SET, 1, 2, 4)
#define W0  asm volatile("s_waitcnt vmcnt(0)" ::: "memory")
#define BAR __builtin_amdgcn_s_barrier()

#define TILE(CUR, NXT, NB, STG, FINAL) do {                                     \
    if (STG) STAGE(NB);                                                         \
    MM3(CUR);                                                                   \
    if (!FINAL) { W0; BAR; RD(NXT, NB); }                                       \
    MMLAST(CUR);                                                                \
} while (0)

// MODE 0 + QK:  qkv Q/K part (normal mfma, permuted A rows) -> Q/K [bh][c][lh]
// MODE 0 + SWP: qkv V part   (swapped)                      -> V   [bh][lh][d]
// MODE 1: S = Q K^T * 0.125 per bh (swapped, f16 out)
// MODE 2: Y = P V per bh (normal, f16 out to y[token][c])
// MODE 3: out = y w_out^T + b_out (swapped, f32 out)
template <int MODE, bool SWP, bool QK>
__global__ __launch_bounds__(256, 2) void g10_k(const f16* __restrict__ A0,
                                                const f16* __restrict__ B0,
                                                void* __restrict__ C0,
                                                void* __restrict__ C1,
                                                const float* __restrict__ bias) {
    __shared__ f16 ldsA[2][8192];   // 2 x 128x64, 32 KiB
    __shared__ f16 ldsB[2][8192];   // 2 x 128x64, 32 KiB

    const int tid = threadIdx.x;
    const int lane = tid & 63;
    const int wid = tid >> 6;
    const int wr = wid >> 1;   // 0..1
    const int wc = wid & 1;    // 0..1

    const int bid = blockIdx.x;
    int tm, tn, bh = 0;
    if constexpr (MODE == 0 && QK) {
        int swz = (bid & 7) * 256 + (bid >> 3);       // 2048 blocks
        tm = (swz >> 3) * 128; tn = (swz & 7) * 128;
    } else if constexpr (MODE == 0) {
        int swz = (bid & 7) * 128 + (bid >> 3);       // 1024 blocks
        tm = (swz >> 2) * 128; tn = (swz & 3) * 128;
    } else if constexpr (MODE == 1 || MODE == 2) {
        int swz = (bid & 7) * 128 + (bid >> 3);       // 1024 blocks
        bh = swz >> 4; tm = ((swz >> 2) & 3) * 128; tn = (swz & 3) * 128;
    } else {
        int swz = (bid & 7) * 128 + (bid >> 3);       // 1024 blocks
        tm = (swz >> 2) * 128; tn = (swz & 3) * 128;
    }

    const size_t bhoff = (MODE == 1 || MODE == 2) ? (size_t)bh * 262144 : 0;
    const char* Ab = (const char*)(A0 + bhoff + (size_t)tm * 512);
    const char* Bb = (const char*)(B0 + bhoff + (size_t)tn * 512);

    // staging swizzle: row r = c*32 + u (u = tid>>3); s(r) = (u&7)^(u>>3)^((c&1)*4)
    const int u = tid >> 3;
    const int colE = ((tid & 7) ^ ((u & 7) ^ (u >> 3))) * 16;
    const int sE = u * 1024 + colE;
    const int sO = sE ^ 64;
    int kb = 0;

    // fragment LDS offsets (f16 units), swizzled: off = r*64 + (c8 ^ s(r))*8
    int aoff[4][2], boff[4][2];
#pragma unroll
    for (int mi = 0; mi < 4; ++mi) {
        int r;
        if constexpr (QK) {
            r = (lane & 15) * 8 + wr * 4 + mi;         // perm rows, e = wr*4+mi
        } else {
            r = wr * 64 + mi * 16 + (lane & 15);
        }
#pragma unroll
        for (int kk = 0; kk < 2; ++kk) {
            int c8 = (lane >> 4) + kk * 4;
            aoff[mi][kk] = r * 64 + (c8 ^ ((r & 7) ^ ((r >> 3) & 7))) * 8;
        }
    }
#pragma unroll
    for (int ni = 0; ni < 4; ++ni) {
        int r = wc * 64 + ni * 16 + (lane & 15);
#pragma unroll
        for (int kk = 0; kk < 2; ++kk) {
            int c8 = (lane >> 4) + kk * 4;
            boff[ni][kk] = r * 64 + (c8 ^ ((r & 7) ^ ((r >> 3) & 7))) * 8;
        }
    }

    f32x4 acc[4][4] = {};
    f16x8 aF0[4][2], bF0[4][2], aF1[4][2], bF1[4][2];

    // prologue: stage tile0 -> buf0, drain, read set0
    STAGE(0);
    W0; BAR;
    RD(0, 0);

    // 8 K-tiles: t0..t6 stage next, t7 final
#pragma unroll 1
    for (int i = 0; i < 3; ++i) {
        TILE(0, 1, 1, true, false);
        TILE(1, 0, 0, true, false);
    }
    TILE(0, 1, 1, true, false);   // t6
    TILE(1, 1, 1, false, true);   // t7 (no stage, no readahead)

    // ---------------- epilogues ----------------
    if constexpr (MODE == 0 && QK) {
        const int b = tm >> 12;
        const int lt = (tm & 4095) >> 3;
        f16* dst = (f16*)(tn < 512 ? C0 : C1);
        const int cb = (tn & 511) + wc * 64;
        const int lh0 = lt + (lane >> 4) * 4;
#pragma unroll
        for (int mi = 0; mi < 4; ++mi) {
            int h = wr * 4 + mi;
#pragma unroll
            for (int ni = 0; ni < 4; ++ni) {
                int c = cb + ni * 16 + (lane & 15);
                *(f16x4*)(dst + ((size_t)((b * 8 + h) * 512 + c)) * 512 + lh0) =
                    cvt4(acc[mi][ni]);
            }
        }
    } else if constexpr (MODE == 0) {      // V, swapped
        f16* dst = (f16*)C0;
#pragma unroll
        for (int mi = 0; mi < 4; ++mi) {
            int t = tm + wr * 64 + mi * 16 + (lane & 15);
            int b = t >> 12, l = t & 4095;
            int h = l & 7, lh = l >> 3;
#pragma unroll
            for (int ni = 0; ni < 4; ++ni) {
                int d0 = tn + wc * 64 + ni * 16 + (lane >> 4) * 4;
                *(f16x4*)(dst + ((size_t)((b * 8 + h) * 512 + lh)) * 512 + d0) =
                    cvt4(acc[mi][ni]);
            }
        }
    } else if constexpr (MODE == 1) {
        f16* S = (f16*)C0 + (size_t)bh * 262144;
#pragma unroll
        for (int mi = 0; mi < 4; ++mi) {
            int cm = tm + wr * 64 + mi * 16 + (lane & 15);
#pragma unroll
            for (int ni = 0; ni < 4; ++ni) {
                int d0 = tn + wc * 64 + ni * 16 + (lane >> 4) * 4;
                *(f16x4*)(S + (size_t)cm * 512 + d0) = cvt4(acc[mi][ni] * 0.125f);
            }
        }
    } else if constexpr (MODE == 2) {
        f16* yb = (f16*)C0;
        const int b = bh >> 3, h = bh & 7;
#pragma unroll
        for (int mi = 0; mi < 4; ++mi) {
            int c0 = tm + wr * 64 + mi * 16 + (lane >> 4) * 4;
#pragma unroll
            for (int ni = 0; ni < 4; ++ni) {
                int l = tn + wc * 64 + ni * 16 + (lane & 15);
                size_t tok = (size_t)b * 4096 + (size_t)l * 8 + h;
                *(f16x4*)(yb + tok * 512 + c0) = cvt4(acc[mi][ni]);
            }
        }
    } else {
        float* O = (float*)C0;
#pragma unroll
        for (int mi = 0; mi < 4; ++mi) {
            int m = tm + wr * 64 + mi * 16 + (lane & 15);
#pragma unroll
            for (int ni = 0; ni < 4; ++ni) {
                int n0 = tn + wc * 64 + ni * 16 + (lane >> 4) * 4;
                float4 bv = *(const float4*)(bias + n0);
                f32x4 v = acc[mi][ni];
                v[0] += bv.x; v[1] += bv.y; v[2] += bv.z; v[3] += bv.w;
                *(f32x4*)(O + (size_t)m * 512 + n0) = v;
            }
        }
    }
}

// ---------------- softmax over 512-wide rows (wave per row, f16 in/out) -------
__global__ __launch_bounds__(256) void softmax_k(const f16* __restrict__ S,
                                                 f16* __restrict__ P) {
    int row = blockIdx.x * 4 + (threadIdx.x >> 6);
    int lane = threadIdx.x & 63;
    f16x8 v = *(const f16x8*)(S + (size_t)row * 512 + lane * 8);
    float f[8];
#pragma unroll
    for (int i = 0; i < 8; ++i) f[i] = (float)v[i];
    float m = f[0];
#pragma unroll
    for (int i = 1; i < 8; ++i) m = fmaxf(m, f[i]);
#pragma unroll
    for (int off = 1; off < 64; off <<= 1) m = fmaxf(m, __shfl_xor(m, off, 64));
    float s = 0.f, e[8];
#pragma unroll
    for (int i = 0; i < 8; ++i) { e[i] = __expf(f[i] - m); s += e[i]; }
#pragma unroll
    for (int off = 1; off < 64; off <<= 1) s += __shfl_xor(s, off, 64);
    float inv = 1.0f / s;
    f16x8 pk;
#pragma unroll
    for (int i = 0; i < 8; ++i) pk[i] = (f16)(e[i] * inv);
    *(f16x8*)(P + (size_t)row * 512 + lane * 8) = pk;
}

// ---------------- launch ------------------------------------------------------
extern "C" void kernel_launch(void* const* d_in, const int* in_sizes, int n_in,
                              void* d_out, int out_size, void* d_ws, size_t ws_size,
                              hipStream_t stream) {
    const float* x = (const float*)d_in[0];
    const float* wqkv = (const float*)d_in[1];
    const float* wout = (const float*)d_in[2];
    const float* bout = (const float*)d_in[3];
    float* out = (float*)d_out;
    char* ws = (char*)d_ws;
    const size_t MBs = 1u << 20;

    f16* xb  = (f16*)(ws + 0);            // 32MB
    f16* wqb = (f16*)(ws + 32 * MBs);     // 1.5MB
    f16* wob = (f16*)(ws + 34 * MBs);     // 0.5MB
    f16* Qb  = (f16*)(ws + 35 * MBs);     // 32MB
    f16* Kb  = (f16*)(ws + 67 * MBs);     // 32MB
    f16* Vb  = (f16*)(ws + 99 * MBs);     // 32MB
    f16* Sb  = (f16*)(ws + 131 * MBs);    // 32MB (total 163MB)
    f16* Pb  = xb;                        // alias: xb dead after V GEMM
    f16* yb  = Qb;                        // alias: Q dead after S GEMM

    prep_k<<<1024, 256, 0, stream>>>(x, wqkv, wout, xb, wqb, wob);
    g10_k<0, false, true><<<2048, 256, 0, stream>>>(xb, wqb, Qb, Kb, nullptr);
    g10_k<0, true, false><<<1024, 256, 0, stream>>>(xb, wqb + (size_t)1024 * 512, Vb, nullptr, nullptr);
    g10_k<1, true, false><<<1024, 256, 0, stream>>>(Qb, Kb, Sb, nullptr, nullptr);
    softmax_k<<<8192, 256, 0, stream>>>(Sb, Pb);
    g10_k<2, false, false><<<1024, 256, 0, stream>>>(Pb, Vb, yb, nullptr, nullptr);
    g10_k<3, true, false><<<1024, 256, 0, stream>>>(yb, wob, out, nullptr, bout);
}